// Round 6
// baseline (281.328 us; speedup 1.0000x reference)
//
#include <hip/hip_runtime.h>
#include <type_traits>

typedef float v2f __attribute__((ext_vector_type(2)));

constexpr int BLOCK = 256;
constexpr int SPT = 2;                     // samples per thread
constexpr int SPB = BLOCK * SPT;           // 512 samples per block
constexpr int HALO_LO = 10;                // l_max(7) + m_max(3)
constexpr int HALO_HI = 3;                 // +m_max for the c (leading) term
constexpr int SIG = SPB + HALO_LO + HALO_HI;
constexpr int NSLOT = 56;                  // 8 lags x 7 radius-slots

// ---------------- compile-time unroll helper ----------------
template<int I, int N, typename F>
__device__ __forceinline__ void unroll_for(F&& f) {
    if constexpr (I < N) {
        f(std::integral_constant<int, I>{});
        unroll_for<I + 1, N>(static_cast<F&&>(f));
    }
}

// y[n] = sum_l x[n-l] * sum_s P_{l,s}(r[n-l+d(s)]),  d: 0,-1,-2,-3,+1,+2,+3
// slot 0 folds a[:,l]+b[:,l,0]+c[:,l,0] (identical radius at m=0).
// Coefficients folded in-kernel into LDS (3.6 KB), read back as wave-uniform
// ds_read_b128 broadcasts into an explicit register double-buffer: in-order
// lgkmcnt, fine-grained waits, prefetch depth bounded by the 128-VGPR cap.
__global__ __launch_bounds__(BLOCK, 4) void gmp_kernel(
    const float* __restrict__ x,
    const float* __restrict__ a_re, const float* __restrict__ a_im,
    const float* __restrict__ b_re, const float* __restrict__ b_im,
    const float* __restrict__ c_re, const float* __restrict__ c_im,
    float* __restrict__ out, int N)
{
    __shared__ float4 scoef[NSLOT * 4];    // slot u: floats [u*16 .. u*16+15]
    __shared__ float sxr[SIG], sxi[SIG], sab[SIG];

    const int t = threadIdx.x;
    const int n0 = blockIdx.x * SPB;

    // ---- fold coefficients into LDS (tiny, L2-hit gathers) ----
    float* scf = (float*)scoef;
    for (int idx = t; idx < 448; idx += BLOCK) {
        int l = idx / 56;
        int rem = idx - l * 56;
        int s = rem >> 3;
        int k = rem & 7;
        int akl = k * 8 + l;               // a[k][l]; b/c[k][l][m] = akl*4 + m
        float re, im;
        if (s == 0) {
            re = a_re[akl] + b_re[akl * 4] + c_re[akl * 4];
            im = a_im[akl] + b_im[akl * 4] + c_im[akl * 4];
        } else if (s <= 3) {
            re = b_re[akl * 4 + s];
            im = b_im[akl * 4 + s];
        } else {
            re = c_re[akl * 4 + (s - 3)];
            im = c_im[akl * 4 + (s - 3)];
        }
        scf[idx * 2]     = re;             // flat = l*112 + s*16 + k*2
        scf[idx * 2 + 1] = im;
    }

    // ---- stage signal + envelope with clipped halo ----
    const float2* x2 = (const float2*)x;
    for (int j = t; j < SIG; j += BLOCK) {
        int g = n0 - HALO_LO + j;
        g = max(0, min(N - 1, g));
        float2 v = x2[g];
        sxr[j] = v.x;
        sxi[j] = v.y;
        sab[j] = __builtin_amdgcn_sqrtf(fmaf(v.x, v.x, v.y * v.y));
    }
    __syncthreads();

    // ---- register-cache this thread's window (compile-time offsets) ----
    const int jb = 2 * t;
    float rv[15];                  // rv[i] = |x| at smem index jb + i
    unroll_for<0, 15>([&](auto I) { rv[I.value] = sab[jb + I.value]; });
    float xr[9], xi[9];            // x at smem index jb + 3 + i
    unroll_for<0, 9>([&](auto I) {
        xr[I.value] = sxr[jb + 3 + I.value];
        xi[I.value] = sxi[jb + 3 + I.value];
    });

    float y0r = 0.f, y0i = 0.f, y1r = 0.f, y1i = 0.f;
    v2f S0 = {0.f, 0.f}, S1 = {0.f, 0.f};

    // double-buffered coefficient registers: 4 x float4 = one slot
    float4 cb[2][4];
    unroll_for<0, 4>([&](auto J) { cb[0][J.value] = scoef[J.value]; });

    unroll_for<0, NSLOT>([&](auto Uc) {
        constexpr int u = Uc.value;
        constexpr int L = u / 7;
        constexpr int Sl = u % 7;
        constexpr int d = (Sl == 0) ? 0 : ((Sl <= 3) ? -Sl : (Sl - 3));
        constexpr int cur = u & 1;

        // prefetch next slot while computing this one
        if constexpr (u + 1 < NSLOT) {
            unroll_for<0, 4>([&](auto J) {
                cb[cur ^ 1][J.value] = scoef[(u + 1) * 4 + J.value];
            });
        }

        const float r0 = rv[10 - L + d];
        const float r1 = rv[11 - L + d];
        const v2f rr0 = {r0, r0};
        const v2f rr1 = {r1, r1};

        auto pair = [&](auto Kc) -> v2f {
            constexpr int k = Kc.value;
            const float4 f = cb[cur][k >> 1];
            if constexpr (k & 1) return v2f{f.z, f.w};
            else                 return v2f{f.x, f.y};
        };

        v2f acc0 = pair(std::integral_constant<int, 7>{});
        v2f acc1 = acc0;
        unroll_for<0, 7>([&](auto Kc) {
            constexpr int k = 6 - Kc.value;
            const v2f wk = pair(std::integral_constant<int, k>{});
            acc0 = __builtin_elementwise_fma(acc0, rr0, wk);
            acc1 = __builtin_elementwise_fma(acc1, rr1, wk);
        });
        S0 += acc0;
        S1 += acc1;

        if constexpr (Sl == 6) {           // end of this lag L: fold into y
            const float x0r = xr[7 - L], x0i = xi[7 - L];
            y0r = fmaf(x0r, S0.x, fmaf(-x0i, S0.y, y0r));
            y0i = fmaf(x0r, S0.y, fmaf( x0i, S0.x, y0i));
            const float x1r = xr[8 - L], x1i = xi[8 - L];
            y1r = fmaf(x1r, S1.x, fmaf(-x1i, S1.y, y1r));
            y1i = fmaf(x1r, S1.y, fmaf( x1i, S1.x, y1i));
            S0 = {0.f, 0.f};
            S1 = {0.f, 0.f};
        }
    });

    const int nb = n0 + 2 * t;
    if (nb + 1 < N) {
        float4* o4 = (float4*)(out + 2 * nb);
        *o4 = make_float4(y0r, y0i, y1r, y1i);
    } else if (nb < N) {
        out[2 * nb]     = y0r;
        out[2 * nb + 1] = y0i;
    }
}

extern "C" void kernel_launch(void* const* d_in, const int* in_sizes, int n_in,
                              void* d_out, int out_size, void* d_ws, size_t ws_size,
                              hipStream_t stream) {
    const float* x    = (const float*)d_in[0];
    const float* a_re = (const float*)d_in[1];
    const float* a_im = (const float*)d_in[2];
    const float* b_re = (const float*)d_in[3];
    const float* b_im = (const float*)d_in[4];
    const float* c_re = (const float*)d_in[5];
    const float* c_im = (const float*)d_in[6];
    float* out = (float*)d_out;

    int N = in_sizes[0] / 2;
    int grid = (N + SPB - 1) / SPB;
    gmp_kernel<<<grid, BLOCK, 0, stream>>>(x, a_re, a_im, b_re, b_im,
                                           c_re, c_im, out, N);
}

// Round 7
// 73.354 us; speedup vs baseline: 3.8352x; 3.8352x over previous
//
#include <hip/hip_runtime.h>
#include <type_traits>

typedef float v2f __attribute__((ext_vector_type(2)));

constexpr int BLOCK = 256;          // 4 waves; wave w owns lags {2w, 2w+1}
constexpr int SPB = 64;             // samples per block (one per lane)
constexpr int HALO_LO = 10;         // l_max(7) + m_max(3)
constexpr int HALO_HI = 3;          // +m_max for the c (leading) term
constexpr int SIG = SPB + HALO_LO + HALO_HI;   // 77

// ---------------- compile-time unroll helper ----------------
template<int I, int N, typename F>
__device__ __forceinline__ void unroll_for(F&& f) {
    if constexpr (I < N) {
        f(std::integral_constant<int, I>{});
        unroll_for<I + 1, N>(static_cast<F&&>(f));
    }
}

// ---------------- kernel 1: fold coefficients ----------------
// w[(l*7+s)*16 + 2k + {0,1}] = (re,im) of W[l][s][k].
// slot 0 = a[:,l] + b[:,l,0] + c[:,l,0]; slots 1..3 = b m=1..3; 4..6 = c m=1..3.
__global__ void prefold_kernel(
    const float* __restrict__ a_re, const float* __restrict__ a_im,
    const float* __restrict__ b_re, const float* __restrict__ b_im,
    const float* __restrict__ c_re, const float* __restrict__ c_im,
    float* __restrict__ w)
{
    int idx = threadIdx.x;
    if (idx >= 448) return;
    int l = idx / 56;
    int rem = idx - l * 56;
    int s = rem >> 3;
    int k = rem & 7;
    int akl = k * 8 + l;                   // a[k][l]; b/c[k][l][m] = akl*4 + m
    float re, im;
    if (s == 0) {
        re = a_re[akl] + b_re[akl * 4] + c_re[akl * 4];
        im = a_im[akl] + b_im[akl * 4] + c_im[akl * 4];
    } else if (s <= 3) {
        re = b_re[akl * 4 + s];
        im = b_im[akl * 4 + s];
    } else {
        re = c_re[akl * 4 + (s - 3)];
        im = c_im[akl * 4 + (s - 3)];
    }
    w[idx * 2]     = re;
    w[idx * 2 + 1] = im;
}

// ---------------- kernel 2: main GMP, lag-split across waves ----------------
// y[n] = sum_L x[n-L] * sum_s P_{L,s}(r[n-L+d(s)]),  d: 0,-1,-2,-3,+1,+2,+3
// Wave w computes the partial sum over lags {2w, 2w+1} for all 64 block
// samples; partials combined through LDS. 8 waves/SIMD resident.
__global__ void gmp_kernel(
    const float* __restrict__ x,
    const float* __restrict__ wbuf,        // folded coefficients (896 floats)
    float* __restrict__ out, int N)
{
    __shared__ float sxr[SIG], sxi[SIG], sab[SIG];
    __shared__ float2 part[BLOCK];

    const int t = threadIdx.x;
    const int n0 = blockIdx.x * SPB;

    // ---- stage signal + envelope with clipped halo (77 entries) ----
    const float2* x2 = (const float2*)x;
    if (t < SIG) {
        int g = n0 - HALO_LO + t;
        g = max(0, min(N - 1, g));
        float2 v = x2[g];
        sxr[t] = v.x;
        sxi[t] = v.y;
        sab[t] = __builtin_amdgcn_sqrtf(fmaf(v.x, v.x, v.y * v.y));
    }
    __syncthreads();

    const int s2 = t & 63;                                   // sample lane
    const int wv = __builtin_amdgcn_readfirstlane(t >> 6);   // wave id 0..3
    const int L0 = 2 * wv;
    const float* wp = wbuf + wv * 224;     // 14 slots x 16 floats

    // radii: rv[i] = |x| at smem index s2 + 6 - L0 + i  (i = 0..7)
    float rv[8];
    {
        const int rb = s2 + 6 - L0;
        unroll_for<0, 8>([&](auto I) { rv[I.value] = sab[rb + I.value]; });
    }
    // x at the two lags
    const float x0r = sxr[s2 + 10 - L0], x0i = sxi[s2 + 10 - L0];
    const float x1r = sxr[s2 +  9 - L0], x1i = sxi[s2 +  9 - L0];

    float yr = 0.f, yi = 0.f;

    unroll_for<0, 2>([&](auto LL) {
        constexpr int ll = LL.value;       // local lag: L = L0 + ll
        v2f S = {0.f, 0.f};
        unroll_for<0, 7>([&](auto Sc) {
            constexpr int s = Sc.value;
            constexpr int d = (s == 0) ? 0 : ((s <= 3) ? -s : (s - 3));
            constexpr int coff = (ll * 7 + s) * 16;
            const float r = rv[4 - ll + d];
            const v2f rr = {r, r};
            v2f acc = {wp[coff + 14], wp[coff + 15]};        // k = 7
            unroll_for<0, 7>([&](auto Kc) {
                constexpr int k = 6 - Kc.value;
                const v2f wk = {wp[coff + 2 * k], wp[coff + 2 * k + 1]};
                acc = __builtin_elementwise_fma(acc, rr, wk);
            });
            S += acc;
        });
        const float xre = ll ? x1r : x0r;
        const float xim = ll ? x1i : x0i;
        yr = fmaf(xre, S.x, fmaf(-xim, S.y, yr));
        yi = fmaf(xre, S.y, fmaf( xim, S.x, yi));
    });

    part[t] = make_float2(yr, yi);
    __syncthreads();

    if (t < SPB) {
        float2 p0 = part[t];
        float2 p1 = part[t + 64];
        float2 p2 = part[t + 128];
        float2 p3 = part[t + 192];
        float2 r;
        r.x = (p0.x + p1.x) + (p2.x + p3.x);
        r.y = (p0.y + p1.y) + (p2.y + p3.y);
        ((float2*)out)[n0 + t] = r;
    }
}

extern "C" void kernel_launch(void* const* d_in, const int* in_sizes, int n_in,
                              void* d_out, int out_size, void* d_ws, size_t ws_size,
                              hipStream_t stream) {
    const float* x    = (const float*)d_in[0];
    const float* a_re = (const float*)d_in[1];
    const float* a_im = (const float*)d_in[2];
    const float* b_re = (const float*)d_in[3];
    const float* b_im = (const float*)d_in[4];
    const float* c_re = (const float*)d_in[5];
    const float* c_im = (const float*)d_in[6];
    float* out = (float*)d_out;
    float* w   = (float*)d_ws;             // 896 floats = 3584 bytes used

    int N = in_sizes[0] / 2;
    prefold_kernel<<<1, 448, 0, stream>>>(a_re, a_im, b_re, b_im, c_re, c_im, w);
    int grid = (N + SPB - 1) / SPB;        // 4096 blocks
    gmp_kernel<<<grid, BLOCK, 0, stream>>>(x, w, out, N);
}

// Round 8
// 72.890 us; speedup vs baseline: 3.8596x; 1.0064x over previous
//
#include <hip/hip_runtime.h>
#include <type_traits>

typedef float v2f __attribute__((ext_vector_type(2)));

// constant address space -> backend emits s_load (scalar pipe, SGPR return)
template <typename T>
using cptr = T __attribute__((address_space(4)))*;

constexpr int BLOCK = 256;          // 4 waves; wave w owns lags {2w, 2w+1}
constexpr int SPB = 128;            // samples per block (2 per lane)
constexpr int HALO_LO = 10;         // l_max(7) + m_max(3)
constexpr int HALO_HI = 3;          // +m_max for the c (leading) term
constexpr int SIG = SPB + HALO_LO + HALO_HI;   // 141

// ---------------- compile-time unroll helper ----------------
template<int I, int N, typename F>
__device__ __forceinline__ void unroll_for(F&& f) {
    if constexpr (I < N) {
        f(std::integral_constant<int, I>{});
        unroll_for<I + 1, N>(static_cast<F&&>(f));
    }
}

// ---------------- kernel 1: fold coefficients ----------------
// w[(l*7+s)*16 + 2k + {0,1}] = (re,im) of W[l][s][k].
// slot 0 = a[:,l] + b[:,l,0] + c[:,l,0]; slots 1..3 = b m=1..3; 4..6 = c m=1..3.
__global__ void prefold_kernel(
    const float* __restrict__ a_re, const float* __restrict__ a_im,
    const float* __restrict__ b_re, const float* __restrict__ b_im,
    const float* __restrict__ c_re, const float* __restrict__ c_im,
    float* __restrict__ w)
{
    int idx = threadIdx.x;
    if (idx >= 448) return;
    int l = idx / 56;
    int rem = idx - l * 56;
    int s = rem >> 3;
    int k = rem & 7;
    int akl = k * 8 + l;                   // a[k][l]; b/c[k][l][m] = akl*4 + m
    float re, im;
    if (s == 0) {
        re = a_re[akl] + b_re[akl * 4] + c_re[akl * 4];
        im = a_im[akl] + b_im[akl * 4] + c_im[akl * 4];
    } else if (s <= 3) {
        re = b_re[akl * 4 + s];
        im = b_im[akl * 4 + s];
    } else {
        re = c_re[akl * 4 + (s - 3)];
        im = c_im[akl * 4 + (s - 3)];
    }
    w[idx * 2]     = re;
    w[idx * 2 + 1] = im;
}

// ---------------- kernel 2: main GMP ----------------
// y[n] = sum_L x[n-L] * sum_s P_{L,s}(r[n-L+d(s)]),  d: 0,-1,-2,-3,+1,+2,+3
// Wave w: lags {2w, 2w+1}; lane: samples {2*s2, 2*s2+1}. Coefficients via
// AS4 (s_load). Partials combined through LDS.
__global__ __launch_bounds__(BLOCK) void gmp_kernel(
    const float* __restrict__ x,
    const float* __restrict__ wbuf,        // folded coefficients (896 floats)
    float* __restrict__ out, int N)
{
    __shared__ float sxr[SIG], sxi[SIG], sab[SIG];
    __shared__ float2 part[4][SPB];

    const int t = threadIdx.x;
    const int n0 = blockIdx.x * SPB;

    // ---- stage signal + envelope with clipped halo ----
    const float2* x2 = (const float2*)x;
    for (int j = t; j < SIG; j += BLOCK) {
        int g = n0 - HALO_LO + j;
        g = max(0, min(N - 1, g));
        float2 v = x2[g];
        sxr[j] = v.x;
        sxi[j] = v.y;
        sab[j] = __builtin_amdgcn_sqrtf(fmaf(v.x, v.x, v.y * v.y));
    }
    __syncthreads();

    const int s2 = t & 63;                                   // sample lane
    const int wv = __builtin_amdgcn_readfirstlane(t >> 6);   // wave id 0..3
    // constant-AS view of this wave's 14 slots (uniform base)
    auto cw = (cptr<const float>)(unsigned long long)(wbuf + wv * 224);

    // window: rv[i] = |x| at smem index rb + i, i = 0..8
    const int rb = 2 * s2 + 6 - 2 * wv;
    float rv[9];
    unroll_for<0, 9>([&](auto I) { rv[I.value] = sab[rb + I.value]; });
    float xvr[3], xvi[3];          // x at smem index rb + 3 + i
    unroll_for<0, 3>([&](auto I) {
        xvr[I.value] = sxr[rb + 3 + I.value];
        xvi[I.value] = sxi[rb + 3 + I.value];
    });

    float y0r = 0.f, y0i = 0.f, y1r = 0.f, y1i = 0.f;

    unroll_for<0, 2>([&](auto LL) {
        constexpr int ll = LL.value;       // local lag: L = 2*wv + ll
        v2f S0 = {0.f, 0.f}, S1 = {0.f, 0.f};
        unroll_for<0, 7>([&](auto Sc) {
            constexpr int s = Sc.value;
            constexpr int d = (s == 0) ? 0 : ((s <= 3) ? -s : (s - 3));
            constexpr int off = ll * 112 + s * 16;
            // uniform scalar coefficient fetch (s_load from AS4)
            float cre[8], cim[8];
            unroll_for<0, 8>([&](auto K) {
                cre[K.value] = cw[off + 2 * K.value];
                cim[K.value] = cw[off + 2 * K.value + 1];
            });
            const float r0 = rv[4 - ll + d];       // sample q=0
            const float r1 = rv[5 - ll + d];       // sample q=1
            const v2f rr0 = {r0, r0};
            const v2f rr1 = {r1, r1};
            v2f acc0 = {cre[7], cim[7]};
            v2f acc1 = acc0;
            unroll_for<0, 7>([&](auto Kc) {
                constexpr int k = 6 - Kc.value;
                const v2f wk = {cre[k], cim[k]};
                acc0 = __builtin_elementwise_fma(acc0, rr0, wk);
                acc1 = __builtin_elementwise_fma(acc1, rr1, wk);
            });
            S0 += acc0;
            S1 += acc1;
        });
        {
            const float xre = xvr[1 - ll], xim = xvi[1 - ll];
            y0r = fmaf(xre, S0.x, fmaf(-xim, S0.y, y0r));
            y0i = fmaf(xre, S0.y, fmaf( xim, S0.x, y0i));
        }
        {
            const float xre = xvr[2 - ll], xim = xvi[2 - ll];
            y1r = fmaf(xre, S1.x, fmaf(-xim, S1.y, y1r));
            y1i = fmaf(xre, S1.y, fmaf( xim, S1.x, y1i));
        }
    });

    part[wv][2 * s2]     = make_float2(y0r, y0i);
    part[wv][2 * s2 + 1] = make_float2(y1r, y1i);
    __syncthreads();

    if (t < SPB) {
        float2 p0 = part[0][t];
        float2 p1 = part[1][t];
        float2 p2 = part[2][t];
        float2 p3 = part[3][t];
        float2 r;
        r.x = (p0.x + p1.x) + (p2.x + p3.x);
        r.y = (p0.y + p1.y) + (p2.y + p3.y);
        const int n = n0 + t;
        if (n < N) ((float2*)out)[n] = r;
    }
}

extern "C" void kernel_launch(void* const* d_in, const int* in_sizes, int n_in,
                              void* d_out, int out_size, void* d_ws, size_t ws_size,
                              hipStream_t stream) {
    const float* x    = (const float*)d_in[0];
    const float* a_re = (const float*)d_in[1];
    const float* a_im = (const float*)d_in[2];
    const float* b_re = (const float*)d_in[3];
    const float* b_im = (const float*)d_in[4];
    const float* c_re = (const float*)d_in[5];
    const float* c_im = (const float*)d_in[6];
    float* out = (float*)d_out;
    float* w   = (float*)d_ws;             // 896 floats = 3584 bytes used

    int N = in_sizes[0] / 2;
    prefold_kernel<<<1, 448, 0, stream>>>(a_re, a_im, b_re, b_im, c_re, c_im, w);
    int grid = (N + SPB - 1) / SPB;        // 2048 blocks
    gmp_kernel<<<grid, BLOCK, 0, stream>>>(x, w, out, N);
}